// Round 11
// baseline (181.347 us; speedup 1.0000x reference)
//
#include <hip/hip_runtime.h>
#include <hip/hip_bf16.h>
#include <math.h>

// Problem constants (B=2, S=2048, D=1024, H=16, HD=64)
#define B_  2
#define S_  2048
#define D_  1024
#define H_  16
#define HD_ 64
#define M_  (B_*S_)     // 4096 rows (b,s)
#define N3  (3*D_)      // 3072 stacked Q|K|V projection cols
#define K_  D_          // 1024 contraction
#define LOG2E 1.44269504088896340736f

typedef unsigned short u16;
typedef __bf16 bf16x8 __attribute__((ext_vector_type(8)));
typedef float  f32x4  __attribute__((ext_vector_type(4)));
typedef float  f32x16 __attribute__((ext_vector_type(16)));
typedef unsigned short u16x4 __attribute__((ext_vector_type(4)));
typedef unsigned short u16x8 __attribute__((ext_vector_type(8)));
typedef unsigned int   u32x4v __attribute__((ext_vector_type(4)));

typedef const __attribute__((address_space(1))) unsigned int gu32;
typedef __attribute__((address_space(3)))       unsigned int lu32;

// async global->LDS, 16B per lane. LDS dest must be wave-uniform base + lane*16.
__device__ __forceinline__ void gload_lds16(const void* g, void* l) {
  __builtin_amdgcn_global_load_lds((gu32*)g, (lu32*)l, 16, 0, 0);
}

// round-to-nearest-even f32 -> bf16
__device__ __forceinline__ u16 f2bf(float f) {
  unsigned u = __builtin_bit_cast(unsigned, f);
  u += 0x7fffu + ((u >> 16) & 1u);
  return (u16)(u >> 16);
}

// pack 2 f32 -> 2 bf16 in one u32 (RNE), single instruction
__device__ __forceinline__ unsigned pk2(float lo, float hi) {
  unsigned d;
  asm("v_cvt_pk_bf16_f32 %0, %1, %2" : "=v"(d) : "v"(lo), "v"(hi));
  return d;
}

// ---------------- prep: f32->bf16 conversions + RoPE tables, one launch --------
// Tables: invf stays f64-derived (bit-compatible with prior rounds); sin/cos now
// f32 device sinf/cosf (<=2 ulp) -- removes slow f64 software transcendentals.
#define NPREP ((M_*D_/4 + 3*(D_*D_/4)) / 256)     // 7168
__global__ void k_prep(const float* __restrict__ hs, const float* __restrict__ Wq,
                       const float* __restrict__ Wk, const float* __restrict__ Wv,
                       u16* __restrict__ Xb, u16* __restrict__ Wb,
                       float* __restrict__ sinT, float* __restrict__ cosT) {
  const int NX = M_*D_/4, NW = D_*D_/4, NTOT = NX + 3*NW;
  int i = blockIdx.x * blockDim.x + threadIdx.x;
  if (i < NTOT) {
    const float4* src; u16* dst; int off;
    if (i < NX)            { src = (const float4*)hs; dst = Xb;           off = i; }
    else if (i < NX+NW)    { src = (const float4*)Wq; dst = Wb;           off = i-NX; }
    else if (i < NX+2*NW)  { src = (const float4*)Wk; dst = Wb + D_*D_;   off = i-NX-NW; }
    else                   { src = (const float4*)Wv; dst = Wb + 2*D_*D_; off = i-NX-2*NW; }
    float4 v = src[off];
    ushort4 o; o.x = f2bf(v.x); o.y = f2bf(v.y); o.z = f2bf(v.z); o.w = f2bf(v.w);
    reinterpret_cast<ushort4*>(dst)[off] = o;
  } else {
    int gid = i - NTOT;                   // [0, 2048*32)
    int s = gid >> 5, j = gid & 31;
    float invf = (float)exp(-(double)j * (log(10000.0) / 32.0));  // f64 exp only
    float ang  = (float)s * invf;         // f32 angle, matches reference rounding
    sinT[gid] = sinf(ang);
    cosT[gid] = cosf(ang);
  }
}

// ---------------- projection GEMM: 2-phase dbuf + T2 XOR-swizzled LDS ----------
#define BM 128
#define BN 128
#define BK 64

__global__ __launch_bounds__(256) void k_gemm(const u16* __restrict__ A,
                                              const u16* __restrict__ Bm,
                                              const float* __restrict__ bq,
                                              const float* __restrict__ bk,
                                              const float* __restrict__ bv,
                                              const float* __restrict__ sinT,
                                              const float* __restrict__ cosT,
                                              u16* __restrict__ Qo,
                                              u16* __restrict__ Ko,
                                              u16* __restrict__ Vt) {
  __shared__ alignas(16) u16 As[2][BM*BK];   // 2 x 16KB
  __shared__ alignas(16) u16 Bs[2][BN*BK];   // 2 x 16KB
  const int t = threadIdx.x;
  const int l = t & 63, w = t >> 6;
  const int wr = w >> 1, wc = w & 1;
  const int lr = l & 15, lg = l >> 4;

  // XCD-chunked block swizzle (768 blocks = 8 XCDs x 96, bijective)
  const int lin = blockIdx.y * (N3/BN) + blockIdx.x;
  const int wk  = (lin & 7) * 96 + (lin >> 3);
  const int m0 = (wk / (N3/BN)) * BM, n0 = (wk % (N3/BN)) * BN;

  // staging: linear LDS dest, pre-swizzled GLOBAL source granule (rule #21)
  const u16* asrc[4]; const u16* bsrc[4];
#pragma unroll
  for (int i = 0; i < 4; ++i) {
    int chunk = i*256 + t;
    int row = chunk >> 3, kc = (chunk & 7) ^ (row & 7);
    asrc[i] = A  + (size_t)(m0+row)*K_ + kc*8;
    bsrc[i] = Bm + (size_t)(n0+row)*K_ + kc*8;
  }

  f32x4 acc[4][4] = {};

  // prologue: stage k0=0 into buf 0
#pragma unroll
  for (int i = 0; i < 4; ++i) {
    int chunk = i*256 + t;
    gload_lds16(asrc[i], &As[0][chunk*8]);
    gload_lds16(bsrc[i], &Bs[0][chunk*8]);
  }
  __syncthreads();

  int cur = 0;
  for (int k0 = 0; k0 < K_; k0 += BK) {
    if (k0 + BK < K_) {
#pragma unroll
      for (int i = 0; i < 4; ++i) {
        int chunk = i*256 + t;
        gload_lds16(asrc[i] + k0 + BK, &As[cur^1][chunk*8]);
        gload_lds16(bsrc[i] + k0 + BK, &Bs[cur^1][chunk*8]);
      }
    }
#pragma unroll
    for (int ks = 0; ks < 2; ++ks) {
      bf16x8 a[4], b[4];
#pragma unroll
      for (int m = 0; m < 4; ++m) {
        int row = wr*64 + m*16 + lr;
        int g   = (ks*4 + lg) ^ (row & 7);
        a[m] = *reinterpret_cast<const bf16x8*>(&As[cur][row*BK + g*8]);
      }
#pragma unroll
      for (int n = 0; n < 4; ++n) {
        int row = wc*64 + n*16 + lr;
        int g   = (ks*4 + lg) ^ (row & 7);
        b[n] = *reinterpret_cast<const bf16x8*>(&Bs[cur][row*BK + g*8]);
      }
#pragma unroll
      for (int m = 0; m < 4; ++m)
#pragma unroll
        for (int n = 0; n < 4; ++n)
          acc[m][n] = __builtin_amdgcn_mfma_f32_16x16x32_bf16(a[m], b[n], acc[m][n], 0, 0, 0);
    }
    __syncthreads();
    cur ^= 1;
  }

  // ---- fused epilogue ----  C/D layout: col = lane&15, row = (lane>>4)*4 + reg
  const int cw0  = n0 + wc*64;
  const int proj = cw0 >> 10;              // 0=Q 1=K 2=V (wave-uniform)
  const int h    = (cw0 & (D_-1)) >> 6;
  const int b    = m0 >> 11;
  const int sb_  = (m0 & (S_-1)) + wr*64;

  if (proj < 2) {
    const float* bias = proj ? bk : bq;
    u16* dst = proj ? Ko : Qo;
    // Q pre-scaled by 0.125*log2(e): folds softmax scale AND exp->exp2
    const float qs = proj ? 1.0f : 0.125f * LOG2E;
    float b1[2], b2[2];
#pragma unroll
    for (int n = 0; n < 2; ++n) {
      b1[n] = bias[h*HD_ + n*16 + lr];
      b2[n] = bias[h*HD_ + n*16 + lr + 32];
    }
#pragma unroll
    for (int m = 0; m < 4; ++m)
#pragma unroll
      for (int r = 0; r < 4; ++r) {
        int s = sb_ + m*16 + lg*4 + r;
        size_t orow = ((size_t)(b*H_ + h)*S_ + s)*HD_;
#pragma unroll
        for (int n = 0; n < 2; ++n) {
          int j = n*16 + lr;
          float x1 = acc[m][n][r]   + b1[n];
          float x2 = acc[m][n+2][r] + b2[n];
          float c  = cosT[(s<<5) + j], sn = sinT[(s<<5) + j];
          dst[orow + j]      = f2bf((x1*c - x2*sn) * qs);
          dst[orow + j + 32] = f2bf((x1*sn + x2*c) * qs);
        }
      }
  } else {
    // V: write Vt (B,H,HD,S), key axis permuted within 16-blocks (bits 2<->3)
    float bb[4];
#pragma unroll
    for (int n = 0; n < 4; ++n) bb[n] = bv[h*HD_ + n*16 + lr];
    const int lgp = ((lg & 1) << 1) | (lg >> 1);
    const int pos0 = sb_ + lgp*4;
#pragma unroll
    for (int m = 0; m < 4; ++m)
#pragma unroll
      for (int n = 0; n < 4; ++n) {
        int hd = n*16 + lr;
        u16x4 o;
#pragma unroll
        for (int r = 0; r < 4; ++r) o[r] = f2bf(acc[m][n][r] + bb[n]);
        *reinterpret_cast<u16x4*>(Vt + ((size_t)(b*H_ + h)*HD_ + hd)*S_ + pos0 + m*16) = o;
      }
  }
}

// ---------------- flash attention: split-K=2, 4 waves x 32 q-rows --------------
// Fixed-max softmax => key-split partials merge by plain ADD (O-numerators and
// lsums). 1024 blocks (32bh x 16qt x 2split) x 256 thr -> 4 blocks/CU, 16
// waves/CU (4/SIMD): doubles overlap vs r10. KT=64; K and V LDS tiles packed
// 2-rows-per-256B + 4-bit XOR swizzle (conflict-reduced both operands).
// Split 0 writes numerators to d_out, split 1 to Opart2; k_red merges+divides.
#define QBW 32
#define NWV 4
#define QTT (QBW*NWV)    // 128 q-rows per block
#define KTL 64
#define NTL 16           // 1024 keys per split / 64

__global__ __launch_bounds__(256, 4) void k_attn(const u16* __restrict__ Q,
                                                 const u16* __restrict__ K,
                                                 const u16* __restrict__ Vt,
                                                 float* __restrict__ out,
                                                 float* __restrict__ Op2,
                                                 float* __restrict__ Lp) {
  __shared__ alignas(16) u16 Ks[2][KTL*HD_];   // 8KB/tile: 32 rows x (2 keys x 64 hd)
  __shared__ alignas(16) u16 Vs[2][HD_*KTL];   // 8KB/tile: 32 rows x (2 hd x 64 keys)
  const int t = threadIdx.x, l = t & 63, w = t >> 6;
  const int q32 = l & 31, hi = l >> 5;

  const int bid = blockIdx.x;
  const int work = (bid & 7) * 128 + (bid >> 3);  // XCD-chunked (1024 % 8 == 0)
  const int bh = work >> 5;                       // 4 bh per XCD
  const int ks = (work >> 4) & 1;                 // key split
  const int q0 = (work & 15) * QTT;

  const u16* Qg = Q  + ((size_t)bh*S_ + q0 + w*QBW)*HD_;
  const u16* Kg = K  + ((size_t)bh*S_ + ks*1024)*HD_;
  const u16* Vg = Vt + (size_t)bh*HD_*S_ + ks*1024;

  // Q B-frags (col=qrow=q32, k = kt*16 + hi*8 + i), loaded once from global
  bf16x8 qf[4];
#pragma unroll
  for (int kt = 0; kt < 4; ++kt)
    qf[kt] = *reinterpret_cast<const bf16x8*>(Qg + (size_t)q32*HD_ + kt*16 + hi*8);

  f32x16 O0 = {}, O1 = {};
  float lp0 = 0.f, lp1 = 0.f, lp2 = 0.f, lp3 = 0.f;

  // staging: LDS slot (row=g>>4, g4=g&15) holds natural granule g4^(row&15).
  // K natural granule: key = row*2 + (g>>3), hd-off (g&7)*8.
  // V natural granule: hd = row*2 + (g>>3), key-off (g&7)*8.
  const u16 *ksrc[2], *vsrc[2];
#pragma unroll
  for (int i = 0; i < 2; ++i) {
    int g  = t + 256*i;                 // [0,512)
    int r_ = g >> 4;
    int kg = (g & 15) ^ (r_ & 15);
    ksrc[i] = Kg + (size_t)(r_*2 + (kg >> 3))*HD_ + (kg & 7)*8;
    vsrc[i] = Vg + (size_t)(r_*2 + (kg >> 3))*S_  + (kg & 7)*8;
  }

  // prologue: stage tile 0 into buf 0
#pragma unroll
  for (int i = 0; i < 2; ++i) {
    gload_lds16(ksrc[i], &Ks[0][(t + 256*i)*8]);
    gload_lds16(vsrc[i], &Vs[0][(t + 256*i)*8]);
  }
  __syncthreads();

  const int rk = q32 >> 1;              // pair-row within tile
  const int kb = (q32 & 1) << 3;        // parity bit of want-granule

  int cur = 0;
  for (int tile = 0; tile < NTL; ++tile) {
    if (tile + 1 < NTL) {
#pragma unroll
      for (int i = 0; i < 2; ++i) {
        gload_lds16(ksrc[i] + (size_t)(tile+1)*KTL*HD_, &Ks[cur^1][(t + 256*i)*8]);
        gload_lds16(vsrc[i] + (tile+1)*KTL,             &Vs[cur^1][(t + 256*i)*8]);
      }
    }

    // QK^T swapped: d[key][qrow]; A = K rows (keys), B = Q (log2 domain)
    f32x16 d0 = {}, d1 = {};
    __builtin_amdgcn_s_setprio(1);
#pragma unroll
    for (int kt = 0; kt < 4; ++kt) {
      const int g0 = (kb | (kt*2 + hi)) ^ rk;
      bf16x8 k0 = *reinterpret_cast<const bf16x8*>(&Ks[cur][(rk*16 + g0)*8]);
      d0 = __builtin_amdgcn_mfma_f32_32x32x16_bf16(k0, qf[kt], d0, 0, 0, 0);
      bf16x8 k1 = *reinterpret_cast<const bf16x8*>(&Ks[cur][((16 + rk)*16 + g0)*8]);
      d1 = __builtin_amdgcn_mfma_f32_32x32x16_bf16(k1, qf[kt], d1, 0, 0, 0);
    }
    __builtin_amdgcn_s_setprio(0);

    // softmax (fixed max): raw v_exp_f32, pack to PV A-frags in native order.
    unsigned pw[4][4];
#pragma unroll
    for (int c = 0; c < 4; ++c) {
      float e[8];
#pragma unroll
      for (int i = 0; i < 8; ++i) {
        float sv = (c < 2) ? d0[(c & 1)*8 + i] : d1[(c & 1)*8 + i];
        e[i] = __builtin_amdgcn_exp2f(sv);
      }
      lp0 += e[0] + e[4];
      lp1 += e[1] + e[5];
      lp2 += e[2] + e[6];
      lp3 += e[3] + e[7];
#pragma unroll
      for (int j = 0; j < 4; ++j) pw[c][j] = pk2(e[2*j], e[2*j+1]);
    }

    // PV: O[qrow][hd] += P * V; B from Vs (hd rows, permuted key axis)
    __builtin_amdgcn_s_setprio(1);
#pragma unroll
    for (int c = 0; c < 4; ++c) {
      u32x4v pv_ = {pw[c][0], pw[c][1], pw[c][2], pw[c][3]};
      bf16x8 pa = __builtin_bit_cast(bf16x8, pv_);
      const int gv = (kb | (c*2 + hi)) ^ rk;
      bf16x8 v0 = *reinterpret_cast<const bf16x8*>(&Vs[cur][(rk*16 + gv)*8]);
      O0 = __builtin_amdgcn_mfma_f32_32x32x16_bf16(pa, v0, O0, 0, 0, 0);
      bf16x8 v1 = *reinterpret_cast<const bf16x8*>(&Vs[cur][((16 + rk)*16 + gv)*8]);
      O1 = __builtin_amdgcn_mfma_f32_32x32x16_bf16(pa, v1, O1, 0, 0, 0);
    }
    __builtin_amdgcn_s_setprio(0);

    __syncthreads();   // drains vmcnt (next buf staged) before swap
    cur ^= 1;
  }

  // partial row sum (this split's keys): fold partials + partner half
  float lsum = (lp0 + lp1) + (lp2 + lp3);
  lsum += __shfl_xor(lsum, 32);
  if (l < 32) Lp[ks*65536 + bh*2048 + q0 + w*QBW + l] = lsum;

  // epilogue: write RAW numerators (k_red divides). split0 -> out, split1 -> Op2
  float* Od = ks ? Op2 : out;
  const int b = bh >> 4, h = bh & 15;
#pragma unroll
  for (int r = 0; r < 16; ++r) {
    int qrow = (r & 3) + 8*(r >> 2) + 4*hi;
    size_t o = (size_t)(b*S_ + q0 + w*QBW + qrow)*D_ + h*HD_;
    Od[o + q32]      = O0[r];
    Od[o + 32 + q32] = O1[r];
  }
}

// ---------------- reduce: out = (out + Op2) / (l0 + l1) ------------------------
__global__ __launch_bounds__(256) void k_red(float* __restrict__ out,
                                             const float* __restrict__ Op2,
                                             const float* __restrict__ Lp) {
  int i4 = blockIdx.x * 256 + threadIdx.x;       // [0, 1048576) float4s
  float4 a = reinterpret_cast<const float4*>(out)[i4];
  float4 b = reinterpret_cast<const float4*>(Op2)[i4];
  int bs = i4 >> 8;                              // b*2048 + s
  int h  = (i4 & 255) >> 4;
  int li = ((bs >> 11)*16 + h)*2048 + (bs & 2047);
  float inv = 1.f / (Lp[li] + Lp[65536 + li]);
  float4 r;
  r.x = (a.x + b.x) * inv; r.y = (a.y + b.y) * inv;
  r.z = (a.z + b.z) * inv; r.w = (a.w + b.w) * inv;
  reinterpret_cast<float4*>(out)[i4] = r;
}

// ---------------- launch ----------------
extern "C" void kernel_launch(void* const* d_in, const int* in_sizes, int n_in,
                              void* d_out, int out_size, void* d_ws, size_t ws_size,
                              hipStream_t stream) {
  const float* hs = (const float*)d_in[0];
  const float* Wq = (const float*)d_in[1];
  const float* bq = (const float*)d_in[2];
  const float* Wk = (const float*)d_in[3];
  const float* bk = (const float*)d_in[4];
  const float* Wv = (const float*)d_in[5];
  const float* bv = (const float*)d_in[6];
  float* out = (float*)d_out;

  // ws layout (~43 MB). Opart2+Lpart share the region with Xb/Wb (lifetimes
  // disjoint: Xb/Wb dead after k_gemm; Opart2/Lpart written by k_attn).
  char* ws = (char*)d_ws;
  float* Op2  = (float*)(ws);                 // 16.78 MB  split-1 O numerators
  float* Lp   = (float*)(ws + 16777216);      //  0.5 MB   lsums [2][65536]
  u16*   Xb   = (u16*)  (ws);                 //  8.0 MB   X bf16 (overlaps Op2)
  u16*   Wb   = (u16*)  (ws + 8388608);       //  6.0 MB   W bf16 (overlaps Op2)
  u16*   Qb   = (u16*)  (ws + 17301504);      //  8.0 MB   Q bf16, pre-scaled
  u16*   Kb   = (u16*)  (ws + 25690112);      //  8.0 MB   K bf16
  u16*   Vtb  = (u16*)  (ws + 34078720);      //  8.0 MB   V^T bf16, key-permuted
  float* sinT = (float*)(ws + 42467328);      //  0.25 MB
  float* cosT = (float*)(ws + 42729472);      //  0.25 MB

  k_prep<<<NPREP + 256, 256, 0, stream>>>(hs, Wq, Wk, Wv, Xb, Wb, sinT, cosT);
  k_gemm<<<dim3(N3/BN, M_/BM), 256, 0, stream>>>(Xb, Wb, bq, bk, bv, sinT, cosT, Qb, Kb, Vtb);
  k_attn<<<1024, 256, 0, stream>>>(Qb, Kb, Vtb, out, Op2, Lp);
  k_red<<<4096, 256, 0, stream>>>(out, Op2, Lp);
}